// Round 1
// baseline (10498.631 us; speedup 1.0000x reference)
//
#include <hip/hip_runtime.h>

#define BB 16
#define NN 2048
#define NITERS 100

// k = log2(e)/eps, eps = 0.05
#define K2E      28.853900817779268f
#define TWO_K2E  57.707801635558536f
#define INV_K2E  0.034657359027997264f
#define LMU      (-11.0f)   // log2(1/2048)

#if __has_builtin(__builtin_amdgcn_exp2f)
#define EXP2F(x) __builtin_amdgcn_exp2f(x)
#else
#define EXP2F(x) exp2f(x)
#endif

// Monotonic-epoch grid barrier: each call, every block adds 1; epoch e is
// complete when cnt >= e*gridDim. No reset -> no reuse race. Requires all
// blocks co-resident (cooperative launch guarantees this).
__device__ __forceinline__ void gbar(int* cnt, int ep) {
    __syncthreads();
    if (threadIdx.x == 0) {
        __threadfence();                      // release our table writes
        atomicAdd(cnt, 1);
        const int target = ep * (int)gridDim.x;
        while (__hip_atomic_load(cnt, __ATOMIC_RELAXED, __HIP_MEMORY_SCOPE_AGENT) < target) {
            __builtin_amdgcn_s_sleep(1);
        }
        __threadfence();                      // acquire others' writes
    }
    __syncthreads();
}

// grid: 256 blocks x 1024 threads. Block b: batch = b>>4, rowblk = b&15
// (128 rows/cols of that batch). Thread: rl = tid&127 (row/col within block),
// part = tid>>7 (0..7) covers 256 of the 2048 summation indices.
__global__ __launch_bounds__(1024) void emd_sinkhorn(
    const float* __restrict__ x, const float* __restrict__ y,
    float4* __restrict__ Xt, float4* __restrict__ Yt,
    float* __restrict__ y2k, int* __restrict__ cnt,
    float* __restrict__ out)
{
    __shared__ float partial[128][9];   // stride 9: conflict-free (gcd(9,32)=1)
    __shared__ float wsum[16];

    const int tid    = threadIdx.x;
    const int rl     = tid & 127;
    const int part   = tid >> 7;
    const int batch  = blockIdx.x >> 4;
    const int rowblk = blockIdx.x & 15;
    const int base   = batch * NN;
    const int gidx   = base + rowblk * 128 + rl;

    // per-thread point data (row i for f-pass/epilogue, col j for g-pass)
    const float x0 = x[3*gidx], x1 = x[3*gidx+1], x2 = x[3*gidx+2];
    const float y0 = y[3*gidx], y1 = y[3*gidx+1], y2 = y[3*gidx+2];

    int ep = 0;

    // ---- prologue: init tables (f=g=0 -> B_j = -k|y|^2, Xt.w unused yet) ----
    if (part == 0) {
        Xt[gidx] = make_float4(TWO_K2E*x0, TWO_K2E*x1, TWO_K2E*x2, 0.0f);
    } else if (part == 1) {
        float q = K2E * (y0*y0 + y1*y1 + y2*y2);
        Yt[gidx] = make_float4(TWO_K2E*y0, TWO_K2E*y1, TWO_K2E*y2, -q);
        y2k[gidx] = q;
    }
    gbar(cnt, ++ep);

    for (int it = 0; it < NITERS; ++it) {
        // ---- f-pass: rows, sum over j via Yt ----
        {
            const float4* __restrict__ T = Yt + base + part * 256;
            float s0 = 0.f, s1 = 0.f, s2 = 0.f, s3 = 0.f;
            #pragma unroll 2
            for (int j = 0; j < 256; j += 4) {
                float4 t0 = T[j], t1 = T[j+1], t2 = T[j+2], t3 = T[j+3];
                s0 += EXP2F(fmaf(x0, t0.x, fmaf(x1, t0.y, fmaf(x2, t0.z, t0.w))));
                s1 += EXP2F(fmaf(x0, t1.x, fmaf(x1, t1.y, fmaf(x2, t1.z, t1.w))));
                s2 += EXP2F(fmaf(x0, t2.x, fmaf(x1, t2.y, fmaf(x2, t2.z, t2.w))));
                s3 += EXP2F(fmaf(x0, t3.x, fmaf(x1, t3.y, fmaf(x2, t3.z, t3.w))));
            }
            partial[rl][part] = (s0 + s1) + (s2 + s3);
        }
        __syncthreads();
        if (tid < 128) {
            float tot = 0.f;
            #pragma unroll
            for (int p = 0; p < 8; ++p) tot += partial[tid][p];
            ((float*)&Xt[base + rowblk*128 + tid])[3] = LMU - __log2f(tot);
        }
        gbar(cnt, ++ep);

        // ---- g-pass: cols, sum over i via Xt ----
        {
            const float4* __restrict__ T = Xt + base + part * 256;
            float s0 = 0.f, s1 = 0.f, s2 = 0.f, s3 = 0.f;
            #pragma unroll 2
            for (int j = 0; j < 256; j += 4) {
                float4 t0 = T[j], t1 = T[j+1], t2 = T[j+2], t3 = T[j+3];
                s0 += EXP2F(fmaf(y0, t0.x, fmaf(y1, t0.y, fmaf(y2, t0.z, t0.w))));
                s1 += EXP2F(fmaf(y0, t1.x, fmaf(y1, t1.y, fmaf(y2, t1.z, t1.w))));
                s2 += EXP2F(fmaf(y0, t2.x, fmaf(y1, t2.y, fmaf(y2, t2.z, t2.w))));
                s3 += EXP2F(fmaf(y0, t3.x, fmaf(y1, t3.y, fmaf(y2, t3.z, t3.w))));
            }
            partial[rl][part] = (s0 + s1) + (s2 + s3);
        }
        __syncthreads();
        if (tid < 128) {
            float tot = 0.f;
            #pragma unroll
            for (int p = 0; p < 8; ++p) tot += partial[tid][p];
            ((float*)&Yt[base + rowblk*128 + tid])[3] = LMU - __log2f(tot);
        }
        gbar(cnt, ++ep);
    }

    // ---- epilogue: sum_j P_ij * C_ij per row; output = sum(P*C)/B ----
    {
        const float  A   = ((const float*)&Xt[gidx])[3];
        const float  x2k = K2E * (x0*x0 + x1*x1 + x2*x2);
        const float4* __restrict__ T = Yt + base + part * 256;
        const float*  __restrict__ Q = y2k + base + part * 256;
        float acc = 0.f;
        #pragma unroll 2
        for (int j = 0; j < 256; ++j) {
            float4 t = T[j];
            float d  = fmaf(x0, t.x, fmaf(x1, t.y, fmaf(x2, t.z, t.w))); // 2kxy + B_j
            float P  = EXP2F(d + A);                                     // 2^(logP)
            float C  = (x2k + Q[j] - (d - t.w)) * INV_K2E;               // |x-y|^2
            C = fmaxf(C, 0.0f);
            acc = fmaf(P, C, acc);
        }
        #pragma unroll
        for (int off = 32; off > 0; off >>= 1) acc += __shfl_down(acc, off, 64);
        if ((tid & 63) == 0) wsum[tid >> 6] = acc;
        __syncthreads();
        if (tid == 0) {
            float bsum = 0.f;
            #pragma unroll
            for (int w = 0; w < 16; ++w) bsum += wsum[w];
            atomicAdd(out, bsum * (1.0f / (float)BB));
        }
    }
}

extern "C" void kernel_launch(void* const* d_in, const int* in_sizes, int n_in,
                              void* d_out, int out_size, void* d_ws, size_t ws_size,
                              hipStream_t stream) {
    const float* x = (const float*)d_in[0];
    const float* y = (const float*)d_in[1];
    float* out = (float*)d_out;
    char* ws = (char*)d_ws;

    int*    cnt = (int*)ws;                                         // 4 B (pad 256)
    float4* Xt  = (float4*)(ws + 256);                              // 512 KB
    float4* Yt  = (float4*)(ws + 256 + (size_t)BB*NN*sizeof(float4));
    float*  y2k = (float*)(ws + 256 + 2*(size_t)BB*NN*sizeof(float4));

    hipMemsetAsync(cnt, 0, sizeof(int), stream);
    hipMemsetAsync(out, 0, sizeof(float), stream);

    void* args[] = {(void*)&x, (void*)&y, (void*)&Xt, (void*)&Yt,
                    (void*)&y2k, (void*)&cnt, (void*)&out};
    hipLaunchCooperativeKernel((const void*)emd_sinkhorn, dim3(256), dim3(1024),
                               args, 0, stream);
}

// Round 2
// 4916.700 us; speedup vs baseline: 2.1353x; 2.1353x over previous
//
#include <hip/hip_runtime.h>

#define BB 16
#define NN 2048
#define NITERS 100

// k = log2(e)/eps, eps = 0.05
#define K2E      28.853900817779268f
#define TWO_K2E  57.707801635558536f
#define INV_K2E  0.034657359027997264f
#define LMU      (-11.0f)   // log2(1/2048)

#if __has_builtin(__builtin_amdgcn_exp2f)
#define EXP2F(x) __builtin_amdgcn_exp2f(x)
#else
#define EXP2F(x) exp2f(x)
#endif

// Per-batch monotonic-epoch barrier: 16 blocks per batch, counter on its own
// 256B-spaced cacheline. Epoch e complete when cnt >= e*16. No reset, no race.
__device__ __forceinline__ void gbar(int* cnt, int ep) {
    __syncthreads();
    if (threadIdx.x == 0) {
        __threadfence();                      // release table writes (cross-XCD)
        atomicAdd(cnt, 1);
        const int target = ep * 16;
        while (__hip_atomic_load(cnt, __ATOMIC_RELAXED, __HIP_MEMORY_SCOPE_AGENT) < target) {
            __builtin_amdgcn_s_sleep(1);
        }
        __threadfence();                      // acquire others' writes
    }
    __syncthreads();
}

// grid: 256 blocks x 1024 threads (1 block/CU). Block b: batch = b>>4,
// rowblk = b&15 (128 rows of that batch). Thread: rl = tid&127, part = tid>>7.
// Wave lanes share `part` -> inner-loop LDS reads are pure broadcast.
__global__ __launch_bounds__(1024) void emd_sinkhorn(
    const float* __restrict__ x, const float* __restrict__ y,
    float4* __restrict__ Xt, float4* __restrict__ Yt,
    float* __restrict__ y2k, int* __restrict__ cntb,
    float* __restrict__ out)
{
    __shared__ float4 tab[NN];          // 32 KB staged opposite-side table
    __shared__ float  qbuf[NN];         // 8 KB, epilogue only (k|y|^2)
    __shared__ float  partial[128][9];  // stride 9: conflict-free
    __shared__ float  wsum[16];

    const int tid    = threadIdx.x;
    const int rl     = tid & 127;
    const int part   = tid >> 7;
    const int batch  = blockIdx.x >> 4;
    const int rowblk = blockIdx.x & 15;
    const int base   = batch * NN;
    const int gidx   = base + rowblk * 128 + rl;
    int* cnt = cntb + batch * 64;       // 256 B spacing between batch counters

    const float x0 = x[3*gidx], x1 = x[3*gidx+1], x2 = x[3*gidx+2];
    const float y0 = y[3*gidx], y1 = y[3*gidx+1], y2 = y[3*gidx+2];

    int ep = 0;

    // ---- prologue: init tables (f=g=0 -> B_j = -k|y|^2) ----
    if (part == 0) {
        Xt[gidx] = make_float4(TWO_K2E*x0, TWO_K2E*x1, TWO_K2E*x2, 0.0f);
    } else if (part == 1) {
        float q = K2E * (y0*y0 + y1*y1 + y2*y2);
        Yt[gidx] = make_float4(TWO_K2E*y0, TWO_K2E*y1, TWO_K2E*y2, -q);
        y2k[gidx] = q;
    }
    gbar(cnt, ++ep);

    for (int it = 0; it < NITERS; ++it) {
        // ---- stage Yt (32 KB, coalesced) then f-pass from LDS ----
        {
            const float4* __restrict__ G = Yt + base;
            tab[2*tid]   = G[2*tid];
            tab[2*tid+1] = G[2*tid+1];
        }
        __syncthreads();
        {
            const float4* __restrict__ T = tab + part * 256;
            float s0 = 0.f, s1 = 0.f, s2 = 0.f, s3 = 0.f;
            #pragma unroll 2
            for (int j = 0; j < 256; j += 4) {
                float4 t0 = T[j], t1 = T[j+1], t2 = T[j+2], t3 = T[j+3];
                s0 += EXP2F(fmaf(x0, t0.x, fmaf(x1, t0.y, fmaf(x2, t0.z, t0.w))));
                s1 += EXP2F(fmaf(x0, t1.x, fmaf(x1, t1.y, fmaf(x2, t1.z, t1.w))));
                s2 += EXP2F(fmaf(x0, t2.x, fmaf(x1, t2.y, fmaf(x2, t2.z, t2.w))));
                s3 += EXP2F(fmaf(x0, t3.x, fmaf(x1, t3.y, fmaf(x2, t3.z, t3.w))));
            }
            partial[rl][part] = (s0 + s1) + (s2 + s3);
        }
        __syncthreads();
        if (tid < 128) {
            float tot = 0.f;
            #pragma unroll
            for (int p = 0; p < 8; ++p) tot += partial[tid][p];
            ((float*)&Xt[base + rowblk*128 + tid])[3] = LMU - __log2f(tot);
        }
        gbar(cnt, ++ep);

        // ---- stage Xt then g-pass from LDS ----
        {
            const float4* __restrict__ G = Xt + base;
            tab[2*tid]   = G[2*tid];
            tab[2*tid+1] = G[2*tid+1];
        }
        __syncthreads();
        {
            const float4* __restrict__ T = tab + part * 256;
            float s0 = 0.f, s1 = 0.f, s2 = 0.f, s3 = 0.f;
            #pragma unroll 2
            for (int j = 0; j < 256; j += 4) {
                float4 t0 = T[j], t1 = T[j+1], t2 = T[j+2], t3 = T[j+3];
                s0 += EXP2F(fmaf(y0, t0.x, fmaf(y1, t0.y, fmaf(y2, t0.z, t0.w))));
                s1 += EXP2F(fmaf(y0, t1.x, fmaf(y1, t1.y, fmaf(y2, t1.z, t1.w))));
                s2 += EXP2F(fmaf(y0, t2.x, fmaf(y1, t2.y, fmaf(y2, t2.z, t2.w))));
                s3 += EXP2F(fmaf(y0, t3.x, fmaf(y1, t3.y, fmaf(y2, t3.z, t3.w))));
            }
            partial[rl][part] = (s0 + s1) + (s2 + s3);
        }
        __syncthreads();
        if (tid < 128) {
            float tot = 0.f;
            #pragma unroll
            for (int p = 0; p < 8; ++p) tot += partial[tid][p];
            ((float*)&Yt[base + rowblk*128 + tid])[3] = LMU - __log2f(tot);
        }
        gbar(cnt, ++ep);
    }

    // ---- epilogue: sum_j P_ij * C_ij per row; output = sum(P*C)/B ----
    {
        const float4* __restrict__ G = Yt + base;
        tab[2*tid]   = G[2*tid];
        tab[2*tid+1] = G[2*tid+1];
        qbuf[tid]        = y2k[base + tid];
        qbuf[tid + 1024] = y2k[base + tid + 1024];
    }
    __syncthreads();
    {
        const float  A   = ((const float*)&Xt[gidx])[3];
        const float  x2k = K2E * (x0*x0 + x1*x1 + x2*x2);
        const float4* __restrict__ T = tab  + part * 256;
        const float*  __restrict__ Q = qbuf + part * 256;
        float acc = 0.f;
        #pragma unroll 2
        for (int j = 0; j < 256; ++j) {
            float4 t = T[j];
            float d  = fmaf(x0, t.x, fmaf(x1, t.y, fmaf(x2, t.z, t.w))); // 2kxy + B_j
            float P  = EXP2F(d + A);                                     // exp(logP)
            float C  = (x2k + Q[j] - (d - t.w)) * INV_K2E;               // |x-y|^2
            C = fmaxf(C, 0.0f);
            acc = fmaf(P, C, acc);
        }
        #pragma unroll
        for (int off = 32; off > 0; off >>= 1) acc += __shfl_down(acc, off, 64);
        if ((tid & 63) == 0) wsum[tid >> 6] = acc;
        __syncthreads();
        if (tid == 0) {
            float bsum = 0.f;
            #pragma unroll
            for (int w = 0; w < 16; ++w) bsum += wsum[w];
            atomicAdd(out, bsum * (1.0f / (float)BB));
        }
    }
}

extern "C" void kernel_launch(void* const* d_in, const int* in_sizes, int n_in,
                              void* d_out, int out_size, void* d_ws, size_t ws_size,
                              hipStream_t stream) {
    const float* x = (const float*)d_in[0];
    const float* y = (const float*)d_in[1];
    float* out = (float*)d_out;
    char* ws = (char*)d_ws;

    int*    cntb = (int*)ws;                                        // 16 × 256 B
    float4* Xt   = (float4*)(ws + 4096);
    float4* Yt   = (float4*)(ws + 4096 + (size_t)BB*NN*sizeof(float4));
    float*  y2k  = (float*)(ws + 4096 + 2*(size_t)BB*NN*sizeof(float4));

    hipMemsetAsync(cntb, 0, 4096, stream);
    hipMemsetAsync(out, 0, sizeof(float), stream);

    void* args[] = {(void*)&x, (void*)&y, (void*)&Xt, (void*)&Yt,
                    (void*)&y2k, (void*)&cntb, (void*)&out};
    hipLaunchCooperativeKernel((const void*)emd_sinkhorn, dim3(256), dim3(1024),
                               args, 0, stream);
}

// Round 3
// 4165.709 us; speedup vs baseline: 2.5203x; 1.1803x over previous
//
#include <hip/hip_runtime.h>

#define BB 16
#define NN 2048
#define NITERS 100

// k = log2(e)/eps, eps = 0.05
#define K2E      28.853900817779268f
#define TWO_K2E  57.707801635558536f
#define INV_K2E  0.034657359027997264f
#define LMU      (-11.0f)   // log2(1/2048)

#if __has_builtin(__builtin_amdgcn_exp2f)
#define EXP2F(x) __builtin_amdgcn_exp2f(x)
#else
#define EXP2F(x) exp2f(x)
#endif

// Per-batch monotonic-epoch barrier: 16 blocks per batch, counter on its own
// 256B-spaced cacheline. Epoch e complete when cnt >= e*16.
__device__ __forceinline__ void gbar(int* cnt, int ep) {
    __syncthreads();
    if (threadIdx.x == 0) {
        __threadfence();                      // release table writes (cross-XCD)
        atomicAdd(cnt, 1);
        const int target = ep * 16;
        while (__hip_atomic_load(cnt, __ATOMIC_RELAXED, __HIP_MEMORY_SCOPE_AGENT) < target) {
            __builtin_amdgcn_s_sleep(1);
        }
        __threadfence();                      // acquire others' writes
    }
    __syncthreads();
}

// grid: 256 blocks x 1024 threads (1 block/CU). Block b: batch=b>>4,
// rowblk=b&15 (128 rows/cols). Wave w owns 8 rows (wave-uniform, in VGPRs);
// lane l reads its OWN tab[j0+lane] (conflict-free b128) and amortizes it
// over 8 rows -> LDS pipe traffic cut 8x vs broadcast layout.
__global__ __launch_bounds__(1024) void emd_sinkhorn(
    const float* __restrict__ x, const float* __restrict__ y,
    float4* __restrict__ Xt, float4* __restrict__ Yt,
    float* __restrict__ y2k, int* __restrict__ cntb,
    float* __restrict__ out)
{
    __shared__ float4 tab[NN];          // 32 KB staged opposite-side table
    __shared__ float  qbuf[NN];         // 8 KB, epilogue only
    __shared__ float  wsum[16];

    const int tid    = threadIdx.x;
    const int lane   = tid & 63;
    const int wave   = tid >> 6;
    const int batch  = blockIdx.x >> 4;
    const int rowblk = blockIdx.x & 15;
    const int base   = batch * NN;
    const int rbase  = base + rowblk * 128 + wave * 8;  // my wave's 8 points
    int* cnt = cntb + batch * 64;       // 256 B spacing between batch counters

    // wave-uniform point data: 8 "row" x-points and 8 "col" y-points
    float xr0[8], xr1[8], xr2[8], yc0[8], yc1[8], yc2[8];
    #pragma unroll
    for (int k = 0; k < 8; ++k) {
        const float* px = x + 3 * (rbase + k);
        xr0[k] = px[0]; xr1[k] = px[1]; xr2[k] = px[2];
        const float* py = y + 3 * (rbase + k);
        yc0[k] = py[0]; yc1[k] = py[1]; yc2[k] = py[2];
    }

    // ---- prologue: init tables (f=g=0 -> B_j = -k|y|^2) ----
    #pragma unroll
    for (int v = 0; v < 2; ++v) {
        int idx = base + tid + v * 1024;
        const float* px = x + 3 * idx;
        Xt[idx] = make_float4(TWO_K2E*px[0], TWO_K2E*px[1], TWO_K2E*px[2], 0.0f);
        const float* py = y + 3 * idx;
        float q = K2E * (py[0]*py[0] + py[1]*py[1] + py[2]*py[2]);
        Yt[idx] = make_float4(TWO_K2E*py[0], TWO_K2E*py[1], TWO_K2E*py[2], -q);
        y2k[idx] = q;
    }
    int ep = 0;
    gbar(cnt, ++ep);

    for (int it = 0; it < NITERS; ++it) {
        // ===== f-pass: stage Yt, rows = x-points =====
        tab[tid]        = Yt[base + tid];
        tab[tid + 1024] = Yt[base + tid + 1024];
        __syncthreads();
        {
            float acc[8] = {0,0,0,0,0,0,0,0};
            for (int j0 = 0; j0 < NN; j0 += 128) {
                float4 ta = tab[j0 + lane];
                float4 tb = tab[j0 + 64 + lane];
                #pragma unroll
                for (int k = 0; k < 8; ++k)
                    acc[k] += EXP2F(fmaf(xr0[k], ta.x, fmaf(xr1[k], ta.y, fmaf(xr2[k], ta.z, ta.w))));
                #pragma unroll
                for (int k = 0; k < 8; ++k)
                    acc[k] += EXP2F(fmaf(xr0[k], tb.x, fmaf(xr1[k], tb.y, fmaf(xr2[k], tb.z, tb.w))));
            }
            // multi-value butterfly: 10 shuffles; row r=( (l&1)<<2 | (l&2) | (l>>2)&1 )
            const bool b0 = lane & 1, b1 = lane & 2, b2 = lane & 4;
            float v4[4], v2[2], v1;
            #pragma unroll
            for (int i = 0; i < 4; ++i) {
                float recv = __shfl_xor(b0 ? acc[i] : acc[i+4], 1, 64);
                v4[i] = (b0 ? acc[i+4] : acc[i]) + recv;
            }
            #pragma unroll
            for (int i = 0; i < 2; ++i) {
                float recv = __shfl_xor(b1 ? v4[i] : v4[i+2], 2, 64);
                v2[i] = (b1 ? v4[i+2] : v4[i]) + recv;
            }
            {
                float recv = __shfl_xor(b2 ? v2[0] : v2[1], 4, 64);
                v1 = (b2 ? v2[1] : v2[0]) + recv;
            }
            v1 += __shfl_xor(v1, 8, 64);
            v1 += __shfl_xor(v1, 16, 64);
            v1 += __shfl_xor(v1, 32, 64);
            if (lane < 8) {
                int r = ((lane & 1) << 2) | (lane & 2) | ((lane >> 2) & 1);
                ((float*)&Xt[rbase + r])[3] = LMU - __log2f(v1);
            }
        }
        gbar(cnt, ++ep);

        // ===== g-pass: stage Xt, cols = y-points =====
        tab[tid]        = Xt[base + tid];
        tab[tid + 1024] = Xt[base + tid + 1024];
        __syncthreads();
        {
            float acc[8] = {0,0,0,0,0,0,0,0};
            for (int j0 = 0; j0 < NN; j0 += 128) {
                float4 ta = tab[j0 + lane];
                float4 tb = tab[j0 + 64 + lane];
                #pragma unroll
                for (int k = 0; k < 8; ++k)
                    acc[k] += EXP2F(fmaf(yc0[k], ta.x, fmaf(yc1[k], ta.y, fmaf(yc2[k], ta.z, ta.w))));
                #pragma unroll
                for (int k = 0; k < 8; ++k)
                    acc[k] += EXP2F(fmaf(yc0[k], tb.x, fmaf(yc1[k], tb.y, fmaf(yc2[k], tb.z, tb.w))));
            }
            const bool b0 = lane & 1, b1 = lane & 2, b2 = lane & 4;
            float v4[4], v2[2], v1;
            #pragma unroll
            for (int i = 0; i < 4; ++i) {
                float recv = __shfl_xor(b0 ? acc[i] : acc[i+4], 1, 64);
                v4[i] = (b0 ? acc[i+4] : acc[i]) + recv;
            }
            #pragma unroll
            for (int i = 0; i < 2; ++i) {
                float recv = __shfl_xor(b1 ? v4[i] : v4[i+2], 2, 64);
                v2[i] = (b1 ? v4[i+2] : v4[i]) + recv;
            }
            {
                float recv = __shfl_xor(b2 ? v2[0] : v2[1], 4, 64);
                v1 = (b2 ? v2[1] : v2[0]) + recv;
            }
            v1 += __shfl_xor(v1, 8, 64);
            v1 += __shfl_xor(v1, 16, 64);
            v1 += __shfl_xor(v1, 32, 64);
            if (lane < 8) {
                int r = ((lane & 1) << 2) | (lane & 2) | ((lane >> 2) & 1);
                ((float*)&Yt[rbase + r])[3] = LMU - __log2f(v1);
            }
        }
        gbar(cnt, ++ep);
    }

    // ===== epilogue: sum_ij P_ij*C_ij; out = total/B =====
    tab[tid]         = Yt[base + tid];
    tab[tid + 1024]  = Yt[base + tid + 1024];
    qbuf[tid]        = y2k[base + tid];
    qbuf[tid + 1024] = y2k[base + tid + 1024];
    __syncthreads();
    {
        float A[8], x2k[8];
        #pragma unroll
        for (int k = 0; k < 8; ++k) {
            A[k]   = ((const float*)&Xt[rbase + k])[3];
            x2k[k] = K2E * (xr0[k]*xr0[k] + xr1[k]*xr1[k] + xr2[k]*xr2[k]);
        }
        float acc[8] = {0,0,0,0,0,0,0,0};
        for (int j0 = 0; j0 < NN; j0 += 64) {
            float4 t = tab[j0 + lane];
            float q  = qbuf[j0 + lane];
            float e  = q + t.w;                  // k|y|^2 + B_j
            #pragma unroll
            for (int k = 0; k < 8; ++k) {
                float d = fmaf(xr0[k], t.x, fmaf(xr1[k], t.y, fmaf(xr2[k], t.z, t.w)));
                float P = EXP2F(d + A[k]);                       // exp(logP)
                float C = fmaxf((x2k[k] + e - d) * INV_K2E, 0.f); // |x-y|^2
                acc[k] = fmaf(P, C, acc[k]);
            }
        }
        float s = 0.f;
        #pragma unroll
        for (int k = 0; k < 8; ++k) s += acc[k];
        #pragma unroll
        for (int m = 32; m > 0; m >>= 1) s += __shfl_xor(s, m, 64);
        if (lane == 0) wsum[wave] = s;
        __syncthreads();
        if (tid == 0) {
            float bsum = 0.f;
            #pragma unroll
            for (int w = 0; w < 16; ++w) bsum += wsum[w];
            atomicAdd(out, bsum * (1.0f / (float)BB));
        }
    }
}

extern "C" void kernel_launch(void* const* d_in, const int* in_sizes, int n_in,
                              void* d_out, int out_size, void* d_ws, size_t ws_size,
                              hipStream_t stream) {
    const float* x = (const float*)d_in[0];
    const float* y = (const float*)d_in[1];
    float* out = (float*)d_out;
    char* ws = (char*)d_ws;

    int*    cntb = (int*)ws;                                        // 16 × 256 B
    float4* Xt   = (float4*)(ws + 4096);
    float4* Yt   = (float4*)(ws + 4096 + (size_t)BB*NN*sizeof(float4));
    float*  y2k  = (float*)(ws + 4096 + 2*(size_t)BB*NN*sizeof(float4));

    hipMemsetAsync(cntb, 0, 4096, stream);
    hipMemsetAsync(out, 0, sizeof(float), stream);

    void* args[] = {(void*)&x, (void*)&y, (void*)&Xt, (void*)&Yt,
                    (void*)&y2k, (void*)&cntb, (void*)&out};
    hipLaunchCooperativeKernel((const void*)emd_sinkhorn, dim3(256), dim3(1024),
                               args, 0, stream);
}

// Round 5
// 3608.073 us; speedup vs baseline: 2.9098x; 1.1546x over previous
//
#include <hip/hip_runtime.h>

#define BB 16
#define NN 2048
#define NITERS 100

// k = log2(e)/eps, eps = 0.05
#define K2E      28.853900817779268f
#define TWO_K2E  57.707801635558536f
#define INV_K2E  0.034657359027997264f
#define INV4K    0.008664339756999316f   // 1/(4k)
#define LMU      (-11.0f)                // log2(1/2048)

#if __has_builtin(__builtin_amdgcn_exp2f)
#define EXP2F(x) __builtin_amdgcn_exp2f(x)
#else
#define EXP2F(x) exp2f(x)
#endif

// Per-batch monotonic-epoch barrier: 16 blocks per batch, counter on its own
// 256B-spaced cacheline. Epoch e complete when cnt >= e*16. Agent-scope
// fences carry correctness regardless of block->XCD placement.
__device__ __forceinline__ void gbar(int* cnt, int ep) {
    __syncthreads();
    if (threadIdx.x == 0) {
        __threadfence();                      // release dual writes
        atomicAdd(cnt, 1);
        const int target = ep * 16;
        while (__hip_atomic_load(cnt, __ATOMIC_RELAXED, __HIP_MEMORY_SCOPE_AGENT) < target) {
            __builtin_amdgcn_s_sleep(1);
        }
        __threadfence();                      // acquire
    }
    __syncthreads();
}

// grid: 256 blocks x 1024 threads (1 block/CU — proven co-op config).
// XCD-local batch grouping (perf only): batch = (blockIdx&7)*2 + (blockIdx>>7)
// puts all 16 blocks of a batch on one XCD under round-robin placement.
// Static 2k*x / 2k*y tables live in LDS whole-kernel (SoA, 48 KB); per pass
// only the 8 KB dual array crosses global memory. Wave owns 8 rows in VGPRs;
// lane owns j (stride-1 LDS reads, conflict-free).
__global__ __launch_bounds__(1024) void emd_sinkhorn(
    const float* __restrict__ x, const float* __restrict__ y,
    float* __restrict__ Af, float* __restrict__ Bf,
    int* __restrict__ cntb, float* __restrict__ out)
{
    __shared__ float sx0[NN], sx1[NN], sx2[NN];   // 24 KB: 2k * x
    __shared__ float sy0[NN], sy1[NN], sy2[NN];   // 24 KB: 2k * y
    __shared__ float sD[NN];                      // 8 KB: staged dual

    const int tid   = threadIdx.x;
    const int lane  = tid & 63;
    const int wave  = tid >> 6;                   // 0..15
    const int batch = ((blockIdx.x & 7) << 1) | (blockIdx.x >> 7);
    const int sub   = (blockIdx.x >> 3) & 15;     // 0..15: my 128-row slice
    const int base  = batch * NN;
    const int r0g   = base + sub * 128 + wave * 8;
    int* cnt = cntb + batch * 64;                 // 256 B spacing

    // ---- stage static tables (once): 2 points per thread, fuse sD=B0 init ----
    #pragma unroll
    for (int v = 0; v < 2; ++v) {
        const int p  = tid + v * 1024;
        const float* px = x + 3 * (size_t)(base + p);
        sx0[p] = TWO_K2E * px[0];
        sx1[p] = TWO_K2E * px[1];
        sx2[p] = TWO_K2E * px[2];
        const float* py = y + 3 * (size_t)(base + p);
        const float a = py[0], b = py[1], c = py[2];
        sy0[p] = TWO_K2E * a;
        sy1[p] = TWO_K2E * b;
        sy2[p] = TWO_K2E * c;
        sD[p]  = -K2E * (a*a + b*b + c*c);        // B0_j = -k|y|^2
    }

    // wave-uniform point data: 8 row x-points, 8 col y-points
    float xr0[8], xr1[8], xr2[8], yc0[8], yc1[8], yc2[8];
    #pragma unroll
    for (int k = 0; k < 8; ++k) {
        const float* px = x + 3 * (size_t)(r0g + k);
        xr0[k] = px[0]; xr1[k] = px[1]; xr2[k] = px[2];
        const float* py = y + 3 * (size_t)(r0g + k);
        yc0[k] = py[0]; yc1[k] = py[1]; yc2[k] = py[2];
    }
    __syncthreads();

    int ep = 0;
    float Aval = 0.f;

    for (int it = 0; it < NITERS; ++it) {
        // ===== f-pass: rows = x, sum over y-points (sy* + sD=B) =====
        if (it > 0) {
            ((float2*)sD)[tid] = ((const float2*)(Bf + base))[tid];
            __syncthreads();
        }
        {
            float acc[8] = {0,0,0,0,0,0,0,0};
            #pragma unroll 2
            for (int j0 = 0; j0 < NN; j0 += 64) {
                const int p = j0 + lane;
                const float t0 = sy0[p], t1 = sy1[p], t2 = sy2[p], tb = sD[p];
                #pragma unroll
                for (int k = 0; k < 8; ++k)
                    acc[k] += EXP2F(fmaf(xr0[k], t0, fmaf(xr1[k], t1, fmaf(xr2[k], t2, tb))));
            }
            // multi-value butterfly; lane L<8 ends with row r(L) (bit0<->bit2 swap)
            const bool b0 = lane & 1, b1 = lane & 2, b2 = lane & 4;
            float v4[4], v2[2], v1;
            #pragma unroll
            for (int i = 0; i < 4; ++i) {
                float recv = __shfl_xor(b0 ? acc[i] : acc[i+4], 1, 64);
                v4[i] = (b0 ? acc[i+4] : acc[i]) + recv;
            }
            #pragma unroll
            for (int i = 0; i < 2; ++i) {
                float recv = __shfl_xor(b1 ? v4[i] : v4[i+2], 2, 64);
                v2[i] = (b1 ? v4[i+2] : v4[i]) + recv;
            }
            {
                float recv = __shfl_xor(b2 ? v2[0] : v2[1], 4, 64);
                v1 = (b2 ? v2[1] : v2[0]) + recv;
            }
            v1 += __shfl_xor(v1, 8, 64);
            v1 += __shfl_xor(v1, 16, 64);
            v1 += __shfl_xor(v1, 32, 64);
            if (lane < 8) {
                int r = ((lane & 1) << 2) | (lane & 2) | ((lane >> 2) & 1);
                Aval = LMU - __log2f(v1);
                Af[r0g + r] = Aval;
            }
        }
        gbar(cnt, ++ep);

        // ===== g-pass: cols = y, sum over x-points (sx* + sD=A) =====
        ((float2*)sD)[tid] = ((const float2*)(Af + base))[tid];
        __syncthreads();
        {
            float acc[8] = {0,0,0,0,0,0,0,0};
            #pragma unroll 2
            for (int j0 = 0; j0 < NN; j0 += 64) {
                const int p = j0 + lane;
                const float t0 = sx0[p], t1 = sx1[p], t2 = sx2[p], ta = sD[p];
                #pragma unroll
                for (int k = 0; k < 8; ++k)
                    acc[k] += EXP2F(fmaf(yc0[k], t0, fmaf(yc1[k], t1, fmaf(yc2[k], t2, ta))));
            }
            const bool b0 = lane & 1, b1 = lane & 2, b2 = lane & 4;
            float v4[4], v2[2], v1;
            #pragma unroll
            for (int i = 0; i < 4; ++i) {
                float recv = __shfl_xor(b0 ? acc[i] : acc[i+4], 1, 64);
                v4[i] = (b0 ? acc[i+4] : acc[i]) + recv;
            }
            #pragma unroll
            for (int i = 0; i < 2; ++i) {
                float recv = __shfl_xor(b1 ? v4[i] : v4[i+2], 2, 64);
                v2[i] = (b1 ? v4[i+2] : v4[i]) + recv;
            }
            {
                float recv = __shfl_xor(b2 ? v2[0] : v2[1], 4, 64);
                v1 = (b2 ? v2[1] : v2[0]) + recv;
            }
            v1 += __shfl_xor(v1, 8, 64);
            v1 += __shfl_xor(v1, 16, 64);
            v1 += __shfl_xor(v1, 32, 64);
            if (lane < 8) {
                int r = ((lane & 1) << 2) | (lane & 2) | ((lane >> 2) & 1);
                Bf[r0g + r] = LMU - __log2f(v1);
            }
        }
        gbar(cnt, ++ep);
    }

    // ===== epilogue: sum_ij P_ij*C_ij; out = total/B =====
    ((float2*)sD)[tid] = ((const float2*)(Bf + base))[tid];   // final B
    __syncthreads();
    {
        // A for my 8 rows via shfl from Aval (r is an involution)
        float Ak[8], x2k[8];
        #pragma unroll
        for (int k = 0; k < 8; ++k) {
            const int src = ((k & 1) << 2) | (k & 2) | ((k >> 2) & 1);
            Ak[k]  = __shfl(Aval, src, 64);
            x2k[k] = K2E * (xr0[k]*xr0[k] + xr1[k]*xr1[k] + xr2[k]*xr2[k]);
        }
        float acc[8] = {0,0,0,0,0,0,0,0};
        for (int j0 = 0; j0 < NN; j0 += 64) {
            const int p = j0 + lane;
            const float t0 = sy0[p], t1 = sy1[p], t2 = sy2[p], tb = sD[p];
            const float q = (t0*t0 + t1*t1 + t2*t2) * INV4K;   // k|y|^2
            #pragma unroll
            for (int k = 0; k < 8; ++k) {
                float d = fmaf(xr0[k], t0, fmaf(xr1[k], t1, fmaf(xr2[k], t2, tb)));
                float P = EXP2F(d + Ak[k]);                         // exp(logP)
                float C = fmaxf((x2k[k] + q - (d - tb)) * INV_K2E, 0.f);
                acc[k] = fmaf(P, C, acc[k]);
            }
        }
        float s = 0.f;
        #pragma unroll
        for (int k = 0; k < 8; ++k) s += acc[k];
        #pragma unroll
        for (int m = 32; m > 0; m >>= 1) s += __shfl_xor(s, m, 64);
        __syncthreads();                 // all waves done reading sD
        if (lane == 0) sD[wave] = s;     // reuse sD as wsum
        __syncthreads();
        if (tid == 0) {
            float bsum = 0.f;
            #pragma unroll
            for (int w = 0; w < 16; ++w) bsum += sD[w];
            atomicAdd(out, bsum * (1.0f / (float)BB));
        }
    }
}

extern "C" void kernel_launch(void* const* d_in, const int* in_sizes, int n_in,
                              void* d_out, int out_size, void* d_ws, size_t ws_size,
                              hipStream_t stream) {
    const float* x = (const float*)d_in[0];
    const float* y = (const float*)d_in[1];
    float* out = (float*)d_out;
    char* ws = (char*)d_ws;

    int*   cntb = (int*)ws;                          // 16 x 256 B
    float* Af   = (float*)(ws + 4096);               // 16*2048 floats = 128 KB
    float* Bf   = (float*)(ws + 4096 + (size_t)BB*NN*sizeof(float));

    hipMemsetAsync(cntb, 0, 4096, stream);
    hipMemsetAsync(out, 0, sizeof(float), stream);

    void* args[] = {(void*)&x, (void*)&y, (void*)&Af, (void*)&Bf,
                    (void*)&cntb, (void*)&out};
    hipLaunchCooperativeKernel((const void*)emd_sinkhorn, dim3(256), dim3(1024),
                               args, 0, stream);
}